// Round 1
// baseline (783.789 us; speedup 1.0000x reference)
//
#include <hip/hip_runtime.h>

typedef unsigned short u16;
typedef unsigned int   u32;
typedef __attribute__((ext_vector_type(4))) float f32x4;
typedef __attribute__((ext_vector_type(8))) short bf16x8;
typedef __attribute__((ext_vector_type(8))) unsigned short u16x8;

#define MFMA16(a,b,c) __builtin_amdgcn_mfma_f32_16x16x32_bf16(a,b,c,0,0,0)

__device__ __forceinline__ u16 f32_bf16(float f){
  u32 u = __builtin_bit_cast(u32, f);
  u = (u + 0x7FFFu + ((u >> 16) & 1u)) >> 16;
  return (u16)u;
}

__device__ __forceinline__ void async_cp16(const u16* g, u16* l){
  __builtin_amdgcn_global_load_lds((const __attribute__((address_space(1))) u32*)g,
                                   (__attribute__((address_space(3))) u32*)l, 16, 0, 0);
}

// ---------------------------------------------------------------- cvt x -> bf16
__global__ __launch_bounds__(256)
void cvt_f32_bf16(const float* __restrict__ in, u16* __restrict__ out){
  size_t i = ((size_t)blockIdx.x * 256 + threadIdx.x) * 8;
  f32x4 a = *(const f32x4*)(in + i);
  f32x4 b = *(const f32x4*)(in + i + 4);
  u16x8 o;
  o[0]=f32_bf16(a[0]); o[1]=f32_bf16(a[1]); o[2]=f32_bf16(a[2]); o[3]=f32_bf16(a[3]);
  o[4]=f32_bf16(b[0]); o[5]=f32_bf16(b[1]); o[6]=f32_bf16(b[2]); o[7]=f32_bf16(b[3]);
  *(u16x8*)(out + i) = o;
}

// ------------------------------------------------- transpose+cvt weights (K,N)->(N,K)
__global__ __launch_bounds__(256)
void transpose_cvt(const float* __restrict__ w, u16* __restrict__ wt, int K, int N){
  __shared__ float tile[32][33];
  int n0 = blockIdx.x * 32, k0 = blockIdx.y * 32;
  int tx = threadIdx.x, ty = threadIdx.y;   // 32 x 8
#pragma unroll
  for (int j = 0; j < 32; j += 8) tile[ty + j][tx] = w[(size_t)(k0 + ty + j) * N + n0 + tx];
  __syncthreads();
#pragma unroll
  for (int j = 0; j < 32; j += 8)
    wt[(size_t)(n0 + ty + j) * K + k0 + tx] = f32_bf16(tile[tx][ty + j]);
}

// --------------------------------------------- m97-style bf16 GEMM: C = A @ Bt^T
// A [M,K] row-major (stride lda), Bt [N,K] row-major, 128x128 tile, BK=64
template<int OUT_BF16, int BIAS>
__global__ __launch_bounds__(256)
void gemm_bt(const u16* __restrict__ A, const u16* __restrict__ Bt,
             void* __restrict__ Cv, const float* __restrict__ bias,
             int K, int lda, int ldc){
  __shared__ u16 sA[128 * 64];
  __shared__ u16 sB[128 * 64];
  const int tid  = threadIdx.x;
  const int lane = tid & 63;
  const int wave = tid >> 6;
  const int lrow = lane & 15, quad = lane >> 4;
  const int m0 = blockIdx.y * 128, n0 = blockIdx.x * 128;
  const int wm = (wave & 1) * 64, wn = (wave >> 1) * 64;

  f32x4 acc[4][4];
#pragma unroll
  for (int i = 0; i < 4; i++)
#pragma unroll
    for (int j = 0; j < 4; j++) acc[i][j] = (f32x4){0.f, 0.f, 0.f, 0.f};

  for (int kt = 0; kt < K; kt += 64){
#pragma unroll
    for (int i = 0; i < 4; i++){
      int c = i * 256 + tid;
      int m = c >> 3, kc = (c & 7) * 8;
      async_cp16(A + (size_t)(m0 + m) * lda + kt + kc, &sA[c * 8]);
    }
#pragma unroll
    for (int i = 0; i < 4; i++){
      int c = i * 256 + tid;
      int n = c >> 3, kc = (c & 7) * 8;
      async_cp16(Bt + (size_t)(n0 + n) * K + kt + kc, &sB[c * 8]);
    }
    __syncthreads();
#pragma unroll
    for (int kk = 0; kk < 2; kk++){
      bf16x8 af[4], bfv[4];
#pragma unroll
      for (int mi = 0; mi < 4; mi++)
        af[mi] = *(const bf16x8*)&sA[(wm + mi * 16 + lrow) * 64 + kk * 32 + quad * 8];
#pragma unroll
      for (int ni = 0; ni < 4; ni++)
        bfv[ni] = *(const bf16x8*)&sB[(wn + ni * 16 + lrow) * 64 + kk * 32 + quad * 8];
#pragma unroll
      for (int mi = 0; mi < 4; mi++)
#pragma unroll
        for (int ni = 0; ni < 4; ni++)
          acc[mi][ni] = MFMA16(af[mi], bfv[ni], acc[mi][ni]);
    }
    __syncthreads();
  }
#pragma unroll
  for (int mi = 0; mi < 4; mi++){
#pragma unroll
    for (int ni = 0; ni < 4; ni++){
      int col = n0 + wn + ni * 16 + lrow;
      float bv = BIAS ? bias[col] : 0.f;
#pragma unroll
      for (int r = 0; r < 4; r++){
        int row = m0 + wm + mi * 16 + quad * 4 + r;
        float v = acc[mi][ni][r];
        if (OUT_BF16) ((u16*)Cv)[(size_t)row * ldc + col] = f32_bf16(v);
        else          ((float*)Cv)[(size_t)row * ldc + col] = v + bv;
      }
    }
  }
}

// ---------------------------------------- per-(b,h): S=Q K^T (over n), norms, softmax
// qkv layout [B,N,2304] bf16: q at col h*48, k at 768+h*48. attnb: [B,H,48,64] bf16
__global__ __launch_bounds__(256)
void attn_stats(const u16* __restrict__ qkvb, const float* __restrict__ temperature,
                u16* __restrict__ attnb){
  const int h = blockIdx.x, b = blockIdx.y;
  const int tid = threadIdx.x, wave = tid >> 6, lane = tid & 63;
  const int lrow = lane & 15, quad = lane >> 4;
  __shared__ struct {
    union {
      struct { u16 q[48 * 136]; u16 k[48 * 136]; } t;
      float red[2 * 15 * 256];
    } u;
    float S[48 * 49];
    float invq[48], invk[48];
  } sm;

  f32x4 acc[15];
#pragma unroll
  for (int t = 0; t < 15; t++) acc[t] = (f32x4){0.f, 0.f, 0.f, 0.f};

  const size_t rowbase = (size_t)b * 3136;
  const int cq = h * 48, ck = 768 + h * 48;

  for (int n0 = 0; n0 < 3136; n0 += 128){
    __syncthreads();
#pragma unroll
    for (int i = 0; i < 3; i++){
      int idx = i * 256 + tid;        // 0..767 over (n 0..127, dgrp 0..5)
      int n = idx / 6, dg = idx - n * 6;
      int gn = n0 + n;
      u16x8 vq, vk;
      if (gn < 3136){
        const u16* p = qkvb + (rowbase + gn) * 2304;
        vq = *(const u16x8*)(p + cq + dg * 8);
        vk = *(const u16x8*)(p + ck + dg * 8);
      } else {
        vq = (u16x8){0,0,0,0,0,0,0,0};
        vk = vq;
      }
#pragma unroll
      for (int j = 0; j < 8; j++){
        sm.u.t.q[(dg * 8 + j) * 136 + n] = vq[j];
        sm.u.t.k[(dg * 8 + j) * 136 + n] = vk[j];
      }
    }
    __syncthreads();
    bf16x8 qf[3], kf[3];
#pragma unroll
    for (int ti = 0; ti < 3; ti++){
      qf[ti] = *(const bf16x8*)&sm.u.t.q[(ti * 16 + lrow) * 136 + wave * 32 + quad * 8];
      kf[ti] = *(const bf16x8*)&sm.u.t.k[(ti * 16 + lrow) * 136 + wave * 32 + quad * 8];
    }
#pragma unroll
    for (int ti = 0; ti < 3; ti++)
#pragma unroll
      for (int tj = 0; tj < 3; tj++)
        acc[ti * 3 + tj] = MFMA16(qf[ti], kf[tj], acc[ti * 3 + tj]);
#pragma unroll
    for (int ti = 0; ti < 3; ti++){
      acc[9  + ti] = MFMA16(qf[ti], qf[ti], acc[9  + ti]);   // Q Q^T (diag = sumsq q)
      acc[12 + ti] = MFMA16(kf[ti], kf[ti], acc[12 + ti]);   // K K^T (diag = sumsq k)
    }
  }
  __syncthreads();
  if (wave < 2){
#pragma unroll
    for (int t = 0; t < 15; t++)
      *(f32x4*)&sm.u.red[(wave * 15 + t) * 256 + lane * 4] = acc[t];
  }
  __syncthreads();
  if (wave >= 2){
#pragma unroll
    for (int t = 0; t < 15; t++){
      f32x4* p = (f32x4*)&sm.u.red[((wave - 2) * 15 + t) * 256 + lane * 4];
      *p = *p + acc[t];
    }
  }
  __syncthreads();
  {
    const int p = tid;
    const int lr = p >> 2, rr = p & 3;
    const int row16 = ((lr >> 4) << 2) + rr, col16 = lr & 15;
#pragma unroll
    for (int t = 0; t < 9; t++){
      float v = sm.u.red[t * 256 + p] + sm.u.red[(15 + t) * 256 + p];
      sm.S[((t / 3) * 16 + row16) * 49 + (t % 3) * 16 + col16] = v;
    }
#pragma unroll
    for (int t = 9; t < 15; t++){
      float v = sm.u.red[t * 256 + p] + sm.u.red[(15 + t) * 256 + p];
      if (row16 == col16){
        if (t < 12) sm.invq[(t - 9)  * 16 + row16] = v;
        else        sm.invk[(t - 12) * 16 + row16] = v;
      }
    }
  }
  __syncthreads();
  if (tid < 96){
    float* arr = (tid < 48) ? sm.invq : sm.invk;
    int d = (tid < 48) ? tid : tid - 48;
    arr[d] = 1.0f / fmaxf(sqrtf(arr[d]), 1e-12f);
  }
  __syncthreads();
  if (tid < 48){
    const int d = tid;
    const float scale = sm.invq[d] * temperature[h];
    float lg[48];
    float mx = -1e30f;
#pragma unroll
    for (int e = 0; e < 48; e++){
      lg[e] = sm.S[d * 49 + e] * scale * sm.invk[e];
      mx = fmaxf(mx, lg[e]);
    }
    float s = 0.f;
#pragma unroll
    for (int e = 0; e < 48; e++){ float ex = __expf(lg[e] - mx); lg[e] = ex; s += ex; }
    const float inv = 1.f / s;
    u16* dst = attnb + ((size_t)(b * 16 + h) * 48 + d) * 64;
#pragma unroll
    for (int e = 0; e < 48; e++) dst[e] = f32_bf16(lg[e] * inv);
#pragma unroll
    for (int e = 48; e < 64; e++) dst[e] = 0;
  }
}

// --------------------------- out_mid[b,n,h*48+d] = sum_e attn[b,h,d,e] * v[b,n,h*48+e]
// writes into the dead q-columns of qkvb (cols 0..767), reads v-columns (1536..2303)
__global__ __launch_bounds__(256)
void attn_apply_v(const u16* __restrict__ qkvb, const u16* __restrict__ attnb,
                  u16* __restrict__ outm){
  const int h = blockIdx.y, b = blockIdx.z;
  const int nb = blockIdx.x * 256;
  const int tid = threadIdx.x, wave = tid >> 6, lane = tid & 63;
  const int lrow = lane & 15, quad = lane >> 4;
  __shared__ u16 sA[48 * 72];
#pragma unroll
  for (int i = 0; i < 2; i++){
    int idx = i * 256 + tid;
    if (idx < 384){
      int d = idx >> 3, eg = idx & 7;
      *(u16x8*)&sA[d * 72 + eg * 8] =
        *(const u16x8*)&attnb[((size_t)(b * 16 + h) * 48 + d) * 64 + eg * 8];
    }
  }
  __syncthreads();
  bf16x8 bfr[3][2];
#pragma unroll
  for (int tj = 0; tj < 3; tj++){
    bfr[tj][0] = *(const bf16x8*)&sA[(tj * 16 + lrow) * 72 + quad * 8];
    bfr[tj][1] = *(const bf16x8*)&sA[(tj * 16 + lrow) * 72 + 32 + quad * 8];
  }
  f32x4 acc[4][3];
#pragma unroll
  for (int i = 0; i < 4; i++)
#pragma unroll
    for (int j = 0; j < 3; j++) acc[i][j] = (f32x4){0.f, 0.f, 0.f, 0.f};

  const size_t vbase = (size_t)b * 3136 * 2304 + 1536 + h * 48;
  const int eo1 = 32 + ((quad < 2) ? quad * 8 : 0);   // clamp e>=48 lanes (B there is 0)
#pragma unroll
  for (int mi = 0; mi < 4; mi++){
    int n = nb + wave * 64 + mi * 16 + lrow;
    int nc = n < 3136 ? n : 3135;
    const u16* vp = qkvb + vbase + (size_t)nc * 2304;
    bf16x8 a0 = *(const bf16x8*)(vp + quad * 8);
    bf16x8 a1 = *(const bf16x8*)(vp + eo1);
#pragma unroll
    for (int tj = 0; tj < 3; tj++){
      acc[mi][tj] = MFMA16(a0, bfr[tj][0], acc[mi][tj]);
      acc[mi][tj] = MFMA16(a1, bfr[tj][1], acc[mi][tj]);
    }
  }
#pragma unroll
  for (int mi = 0; mi < 4; mi++)
#pragma unroll
    for (int tj = 0; tj < 3; tj++){
      int col = h * 48 + tj * 16 + lrow;
#pragma unroll
      for (int r = 0; r < 4; r++){
        int n = nb + wave * 64 + mi * 16 + quad * 4 + r;
        if (n < 3136)
          outm[((size_t)b * 3136 + n) * 2304 + col] = f32_bf16(acc[mi][tj][r]);
      }
    }
}

extern "C" void kernel_launch(void* const* d_in, const int* in_sizes, int n_in,
                              void* d_out, int out_size, void* d_ws, size_t ws_size,
                              hipStream_t stream){
  const float* x      = (const float*)d_in[0];   // [16,3136,768]
  const float* qkv_w  = (const float*)d_in[1];   // [768,2304]
  const float* temp   = (const float*)d_in[2];   // [16]
  const float* proj_w = (const float*)d_in[3];   // [768,768]
  const float* proj_b = (const float*)d_in[4];   // [768]
  float* out = (float*)d_out;
  char* ws = (char*)d_ws;

  // workspace layout (bytes)
  const size_t OFF_XB   = 0;            // 50176*768*2   = 77,070,336
  const size_t OFF_WQ   = 77070336;     // 2304*768*2    =  3,538,944
  const size_t OFF_WP   = 80609280;     // 768*768*2     =  1,179,648
  const size_t OFF_QKV  = 81788928;     // 50176*2304*2  = 231,211,008
  const size_t OFF_ATTN = 312999936;    // 16*16*48*64*2 =  1,572,864  (end ~314.6 MB)

  u16* xb    = (u16*)(ws + OFF_XB);
  u16* wqt   = (u16*)(ws + OFF_WQ);
  u16* wpt   = (u16*)(ws + OFF_WP);
  u16* qkvb  = (u16*)(ws + OFF_QKV);
  u16* attnb = (u16*)(ws + OFF_ATTN);

  // 1) casts / transposes
  cvt_f32_bf16<<<dim3(18816), dim3(256), 0, stream>>>(x, xb);
  transpose_cvt<<<dim3(2304 / 32, 768 / 32), dim3(32, 8), 0, stream>>>(qkv_w, wqt, 768, 2304);
  transpose_cvt<<<dim3(768 / 32, 768 / 32), dim3(32, 8), 0, stream>>>(proj_w, wpt, 768, 768);
  // 2) qkv = x @ qkv_w  (bf16 out, [B,N,2304])
  gemm_bt<1, 0><<<dim3(18, 392), dim3(256), 0, stream>>>(xb, wqt, qkvb, nullptr, 768, 768, 2304);
  // 3) per-(b,h) Gram + norms + softmax -> attn [B,H,48,64] (cols 48..63 zero)
  attn_stats<<<dim3(16, 16), dim3(256), 0, stream>>>(qkvb, temp, attnb);
  // 4) attn @ v -> overwrite q-columns of qkvb
  attn_apply_v<<<dim3(13, 16, 16), dim3(256), 0, stream>>>(qkvb, attnb, qkvb);
  // 5) out = out_mid @ proj_w + proj_b (fp32 out)
  gemm_bt<0, 1><<<dim3(6, 392), dim3(256), 0, stream>>>(qkvb, wpt, out, proj_b, 768, 2304, 768);
}

// Round 2
// 700.881 us; speedup vs baseline: 1.1183x; 1.1183x over previous
//
#include <hip/hip_runtime.h>

typedef unsigned short u16;
typedef unsigned int   u32;
typedef __attribute__((ext_vector_type(4))) float f32x4;
typedef __attribute__((ext_vector_type(8))) short bf16x8;
typedef __attribute__((ext_vector_type(8))) unsigned short u16x8;

#define MFMA16(a,b,c) __builtin_amdgcn_mfma_f32_16x16x32_bf16(a,b,c,0,0,0)

__device__ __forceinline__ u16 f32_bf16(float f){
  u32 u = __builtin_bit_cast(u32, f);
  u = (u + 0x7FFFu + ((u >> 16) & 1u)) >> 16;
  return (u16)u;
}

__device__ __forceinline__ void async_cp16(const u16* g, u16* l){
  __builtin_amdgcn_global_load_lds((const __attribute__((address_space(1))) u32*)g,
                                   (__attribute__((address_space(3))) u32*)l, 16, 0, 0);
}

// ---------------------------------------------------------------- cvt x -> bf16
__global__ __launch_bounds__(256)
void cvt_f32_bf16(const float* __restrict__ in, u16* __restrict__ out){
  size_t i = ((size_t)blockIdx.x * 256 + threadIdx.x) * 8;
  f32x4 a = *(const f32x4*)(in + i);
  f32x4 b = *(const f32x4*)(in + i + 4);
  u16x8 o;
  o[0]=f32_bf16(a[0]); o[1]=f32_bf16(a[1]); o[2]=f32_bf16(a[2]); o[3]=f32_bf16(a[3]);
  o[4]=f32_bf16(b[0]); o[5]=f32_bf16(b[1]); o[6]=f32_bf16(b[2]); o[7]=f32_bf16(b[3]);
  *(u16x8*)(out + i) = o;
}

// ------------------------------------------------- transpose+cvt weights (K,N)->(N,K)
__global__ __launch_bounds__(256)
void transpose_cvt(const float* __restrict__ w, u16* __restrict__ wt, int K, int N){
  __shared__ float tile[32][33];
  int n0 = blockIdx.x * 32, k0 = blockIdx.y * 32;
  int tx = threadIdx.x, ty = threadIdx.y;   // 32 x 8
#pragma unroll
  for (int j = 0; j < 32; j += 8) tile[ty + j][tx] = w[(size_t)(k0 + ty + j) * N + n0 + tx];
  __syncthreads();
#pragma unroll
  for (int j = 0; j < 32; j += 8)
    wt[(size_t)(n0 + ty + j) * K + k0 + tx] = f32_bf16(tile[tx][ty + j]);
}

// --------------------------------------------- m97-style bf16 GEMM: C = A @ Bt^T
// A [M,K] row-major (stride lda), Bt [N,K] row-major, 128x128 tile, BK=64.
// LDS layout XOR-swizzled: row m's 16B chunk kc stored at chunk pos kc^(m&7),
// expressed by permuting the *global source* chunk (global_load_lds dest must
// stay linear). Kills the 16-lane/4-bank quad conflict of the 128B-stride tile.
template<int OUT_BF16, int BIAS>
__global__ __launch_bounds__(256)
void gemm_bt(const u16* __restrict__ A, const u16* __restrict__ Bt,
             void* __restrict__ Cv, const float* __restrict__ bias,
             int K, int lda, int ldc){
  __shared__ u16 sA[128 * 64];
  __shared__ u16 sB[128 * 64];
  const int tid  = threadIdx.x;
  const int lane = tid & 63;
  const int wave = tid >> 6;
  const int lrow = lane & 15, quad = lane >> 4;
  const int m0 = blockIdx.y * 128, n0 = blockIdx.x * 128;
  const int wm = (wave & 1) * 64, wn = (wave >> 1) * 64;
  const int sw = lrow & 7;                       // row&7 for all fragment rows
  const int col0 = ((0 * 4 + quad) ^ sw) * 8;    // kk=0 swizzled chunk offset (u16)
  const int col1 = ((1 * 4 + quad) ^ sw) * 8;    // kk=1

  f32x4 acc[4][4];
#pragma unroll
  for (int i = 0; i < 4; i++)
#pragma unroll
    for (int j = 0; j < 4; j++) acc[i][j] = (f32x4){0.f, 0.f, 0.f, 0.f};

  for (int kt = 0; kt < K; kt += 64){
#pragma unroll
    for (int i = 0; i < 4; i++){
      int c = i * 256 + tid;
      int m = c >> 3, kc = (c & 7) ^ (m & 7);    // inverse swizzle on global source
      async_cp16(A + (size_t)(m0 + m) * lda + kt + kc * 8, &sA[c * 8]);
    }
#pragma unroll
    for (int i = 0; i < 4; i++){
      int c = i * 256 + tid;
      int n = c >> 3, kc = (c & 7) ^ (n & 7);
      async_cp16(Bt + (size_t)(n0 + n) * K + kt + kc * 8, &sB[c * 8]);
    }
    __syncthreads();
#pragma unroll
    for (int kk = 0; kk < 2; kk++){
      const int col = kk ? col1 : col0;
      bf16x8 af[4], bfv[4];
#pragma unroll
      for (int mi = 0; mi < 4; mi++)
        af[mi] = *(const bf16x8*)&sA[(wm + mi * 16 + lrow) * 64 + col];
#pragma unroll
      for (int ni = 0; ni < 4; ni++)
        bfv[ni] = *(const bf16x8*)&sB[(wn + ni * 16 + lrow) * 64 + col];
#pragma unroll
      for (int mi = 0; mi < 4; mi++)
#pragma unroll
        for (int ni = 0; ni < 4; ni++)
          acc[mi][ni] = MFMA16(af[mi], bfv[ni], acc[mi][ni]);
    }
    __syncthreads();
  }
#pragma unroll
  for (int mi = 0; mi < 4; mi++){
#pragma unroll
    for (int ni = 0; ni < 4; ni++){
      int col = n0 + wn + ni * 16 + lrow;
      float bv = BIAS ? bias[col] : 0.f;
#pragma unroll
      for (int r = 0; r < 4; r++){
        int row = m0 + wm + mi * 16 + quad * 4 + r;
        float v = acc[mi][ni][r];
        if (OUT_BF16) ((u16*)Cv)[(size_t)row * ldc + col] = f32_bf16(v);
        else          ((float*)Cv)[(size_t)row * ldc + col] = v + bv;
      }
    }
  }
}

// ---------------------------------------- per-(b,h): S=Q K^T (over n), norms, softmax
// qkv layout [B,N,2304] bf16: q at col h*48, k at 768+h*48. attnb: [B,H,48,64] bf16
__global__ __launch_bounds__(256)
void attn_stats(const u16* __restrict__ qkvb, const float* __restrict__ temperature,
                u16* __restrict__ attnb){
  const int h = blockIdx.x, b = blockIdx.y;
  const int tid = threadIdx.x, wave = tid >> 6, lane = tid & 63;
  const int lrow = lane & 15, quad = lane >> 4;
  __shared__ struct {
    union {
      struct { u16 q[48 * 136]; u16 k[48 * 136]; } t;
      float red[2 * 15 * 256];
    } u;
    float S[48 * 49];
    float invq[48], invk[48];
  } sm;

  f32x4 acc[15];
#pragma unroll
  for (int t = 0; t < 15; t++) acc[t] = (f32x4){0.f, 0.f, 0.f, 0.f};

  const size_t rowbase = (size_t)b * 3136;
  const int cq = h * 48, ck = 768 + h * 48;

  for (int n0 = 0; n0 < 3136; n0 += 128){
    __syncthreads();
#pragma unroll
    for (int i = 0; i < 3; i++){
      int idx = i * 256 + tid;        // 0..767 over (n 0..127, dgrp 0..5)
      int n = idx / 6, dg = idx - n * 6;
      int gn = n0 + n;
      u16x8 vq, vk;
      if (gn < 3136){
        const u16* p = qkvb + (rowbase + gn) * 2304;
        vq = *(const u16x8*)(p + cq + dg * 8);
        vk = *(const u16x8*)(p + ck + dg * 8);
      } else {
        vq = (u16x8){0,0,0,0,0,0,0,0};
        vk = vq;
      }
#pragma unroll
      for (int j = 0; j < 8; j++){
        sm.u.t.q[(dg * 8 + j) * 136 + n] = vq[j];
        sm.u.t.k[(dg * 8 + j) * 136 + n] = vk[j];
      }
    }
    __syncthreads();
    bf16x8 qf[3], kf[3];
#pragma unroll
    for (int ti = 0; ti < 3; ti++){
      qf[ti] = *(const bf16x8*)&sm.u.t.q[(ti * 16 + lrow) * 136 + wave * 32 + quad * 8];
      kf[ti] = *(const bf16x8*)&sm.u.t.k[(ti * 16 + lrow) * 136 + wave * 32 + quad * 8];
    }
#pragma unroll
    for (int ti = 0; ti < 3; ti++)
#pragma unroll
      for (int tj = 0; tj < 3; tj++)
        acc[ti * 3 + tj] = MFMA16(qf[ti], kf[tj], acc[ti * 3 + tj]);
#pragma unroll
    for (int ti = 0; ti < 3; ti++){
      acc[9  + ti] = MFMA16(qf[ti], qf[ti], acc[9  + ti]);   // Q Q^T (diag = sumsq q)
      acc[12 + ti] = MFMA16(kf[ti], kf[ti], acc[12 + ti]);   // K K^T (diag = sumsq k)
    }
  }
  __syncthreads();
  if (wave < 2){
#pragma unroll
    for (int t = 0; t < 15; t++)
      *(f32x4*)&sm.u.red[(wave * 15 + t) * 256 + lane * 4] = acc[t];
  }
  __syncthreads();
  if (wave >= 2){
#pragma unroll
    for (int t = 0; t < 15; t++){
      f32x4* p = (f32x4*)&sm.u.red[((wave - 2) * 15 + t) * 256 + lane * 4];
      *p = *p + acc[t];
    }
  }
  __syncthreads();
  {
    const int p = tid;
    const int lr = p >> 2, rr = p & 3;
    const int row16 = ((lr >> 4) << 2) + rr, col16 = lr & 15;
#pragma unroll
    for (int t = 0; t < 9; t++){
      float v = sm.u.red[t * 256 + p] + sm.u.red[(15 + t) * 256 + p];
      sm.S[((t / 3) * 16 + row16) * 49 + (t % 3) * 16 + col16] = v;
    }
#pragma unroll
    for (int t = 9; t < 15; t++){
      float v = sm.u.red[t * 256 + p] + sm.u.red[(15 + t) * 256 + p];
      if (row16 == col16){
        if (t < 12) sm.invq[(t - 9)  * 16 + row16] = v;
        else        sm.invk[(t - 12) * 16 + row16] = v;
      }
    }
  }
  __syncthreads();
  if (tid < 96){
    float* arr = (tid < 48) ? sm.invq : sm.invk;
    int d = (tid < 48) ? tid : tid - 48;
    arr[d] = 1.0f / fmaxf(sqrtf(arr[d]), 1e-12f);
  }
  __syncthreads();
  if (tid < 48){
    const int d = tid;
    const float scale = sm.invq[d] * temperature[h];
    float lg[48];
    float mx = -1e30f;
#pragma unroll
    for (int e = 0; e < 48; e++){
      lg[e] = sm.S[d * 49 + e] * scale * sm.invk[e];
      mx = fmaxf(mx, lg[e]);
    }
    float s = 0.f;
#pragma unroll
    for (int e = 0; e < 48; e++){ float ex = __expf(lg[e] - mx); lg[e] = ex; s += ex; }
    const float inv = 1.f / s;
    u16* dst = attnb + ((size_t)(b * 16 + h) * 48 + d) * 64;
#pragma unroll
    for (int e = 0; e < 48; e++) dst[e] = f32_bf16(lg[e] * inv);
#pragma unroll
    for (int e = 48; e < 64; e++) dst[e] = 0;
  }
}

// --------------------------- out_mid[b,n,h*48+d] = sum_e attn[b,h,d,e] * v[b,n,h*48+e]
// writes into the dead q-columns of qkvb (cols 0..767), reads v-columns (1536..2303)
__global__ __launch_bounds__(256)
void attn_apply_v(const u16* __restrict__ qkvb, const u16* __restrict__ attnb,
                  u16* __restrict__ outm){
  const int h = blockIdx.y, b = blockIdx.z;
  const int nb = blockIdx.x * 256;
  const int tid = threadIdx.x, wave = tid >> 6, lane = tid & 63;
  const int lrow = lane & 15, quad = lane >> 4;
  __shared__ u16 sA[48 * 72];
#pragma unroll
  for (int i = 0; i < 2; i++){
    int idx = i * 256 + tid;
    if (idx < 384){
      int d = idx >> 3, eg = idx & 7;
      *(u16x8*)&sA[d * 72 + eg * 8] =
        *(const u16x8*)&attnb[((size_t)(b * 16 + h) * 48 + d) * 64 + eg * 8];
    }
  }
  __syncthreads();
  bf16x8 bfr[3][2];
#pragma unroll
  for (int tj = 0; tj < 3; tj++){
    bfr[tj][0] = *(const bf16x8*)&sA[(tj * 16 + lrow) * 72 + quad * 8];
    bfr[tj][1] = *(const bf16x8*)&sA[(tj * 16 + lrow) * 72 + 32 + quad * 8];
  }
  f32x4 acc[4][3];
#pragma unroll
  for (int i = 0; i < 4; i++)
#pragma unroll
    for (int j = 0; j < 3; j++) acc[i][j] = (f32x4){0.f, 0.f, 0.f, 0.f};

  const size_t vbase = (size_t)b * 3136 * 2304 + 1536 + h * 48;
  const int eo1 = 32 + ((quad < 2) ? quad * 8 : 0);   // clamp e>=48 lanes (B there is 0)
#pragma unroll
  for (int mi = 0; mi < 4; mi++){
    int n = nb + wave * 64 + mi * 16 + lrow;
    int nc = n < 3136 ? n : 3135;
    const u16* vp = qkvb + vbase + (size_t)nc * 2304;
    bf16x8 a0 = *(const bf16x8*)(vp + quad * 8);
    bf16x8 a1 = *(const bf16x8*)(vp + eo1);
#pragma unroll
    for (int tj = 0; tj < 3; tj++){
      acc[mi][tj] = MFMA16(a0, bfr[tj][0], acc[mi][tj]);
      acc[mi][tj] = MFMA16(a1, bfr[tj][1], acc[mi][tj]);
    }
  }
#pragma unroll
  for (int mi = 0; mi < 4; mi++)
#pragma unroll
    for (int tj = 0; tj < 3; tj++){
      int col = h * 48 + tj * 16 + lrow;
#pragma unroll
      for (int r = 0; r < 4; r++){
        int n = nb + wave * 64 + mi * 16 + quad * 4 + r;
        if (n < 3136)
          outm[((size_t)b * 3136 + n) * 2304 + col] = f32_bf16(acc[mi][tj][r]);
      }
    }
}

extern "C" void kernel_launch(void* const* d_in, const int* in_sizes, int n_in,
                              void* d_out, int out_size, void* d_ws, size_t ws_size,
                              hipStream_t stream){
  const float* x      = (const float*)d_in[0];   // [16,3136,768]
  const float* qkv_w  = (const float*)d_in[1];   // [768,2304]
  const float* temp   = (const float*)d_in[2];   // [16]
  const float* proj_w = (const float*)d_in[3];   // [768,768]
  const float* proj_b = (const float*)d_in[4];   // [768]
  float* out = (float*)d_out;
  char* ws = (char*)d_ws;

  // workspace layout (bytes)
  const size_t OFF_XB   = 0;            // 50176*768*2   = 77,070,336
  const size_t OFF_WQ   = 77070336;     // 2304*768*2    =  3,538,944
  const size_t OFF_WP   = 80609280;     // 768*768*2     =  1,179,648
  const size_t OFF_QKV  = 81788928;     // 50176*2304*2  = 231,211,008
  const size_t OFF_ATTN = 312999936;    // 16*16*48*64*2 =  1,572,864  (end ~314.6 MB)

  u16* xb    = (u16*)(ws + OFF_XB);
  u16* wqt   = (u16*)(ws + OFF_WQ);
  u16* wpt   = (u16*)(ws + OFF_WP);
  u16* qkvb  = (u16*)(ws + OFF_QKV);
  u16* attnb = (u16*)(ws + OFF_ATTN);

  // 1) casts / transposes
  cvt_f32_bf16<<<dim3(18816), dim3(256), 0, stream>>>(x, xb);
  transpose_cvt<<<dim3(2304 / 32, 768 / 32), dim3(32, 8), 0, stream>>>(qkv_w, wqt, 768, 2304);
  transpose_cvt<<<dim3(768 / 32, 768 / 32), dim3(32, 8), 0, stream>>>(proj_w, wpt, 768, 768);
  // 2) qkv = x @ qkv_w  (bf16 out, [B,N,2304])
  gemm_bt<1, 0><<<dim3(18, 392), dim3(256), 0, stream>>>(xb, wqt, qkvb, nullptr, 768, 768, 2304);
  // 3) per-(b,h) Gram + norms + softmax -> attn [B,H,48,64] (cols 48..63 zero)
  attn_stats<<<dim3(16, 16), dim3(256), 0, stream>>>(qkvb, temp, attnb);
  // 4) attn @ v -> overwrite q-columns of qkvb
  attn_apply_v<<<dim3(13, 16, 16), dim3(256), 0, stream>>>(qkvb, attnb, qkvb);
  // 5) out = out_mid @ proj_w + proj_b (fp32 out)
  gemm_bt<0, 1><<<dim3(6, 392), dim3(256), 0, stream>>>(qkvb, wpt, out, proj_b, 768, 2304, 768);
}

// Round 3
// 683.270 us; speedup vs baseline: 1.1471x; 1.0258x over previous
//
#include <hip/hip_runtime.h>

typedef unsigned short u16;
typedef unsigned int   u32;
typedef __attribute__((ext_vector_type(4))) float f32x4;
typedef __attribute__((ext_vector_type(8))) short bf16x8;
typedef __attribute__((ext_vector_type(8))) unsigned short u16x8;

#define MFMA16(a,b,c) __builtin_amdgcn_mfma_f32_16x16x32_bf16(a,b,c,0,0,0)

// head-panel stride: 50176 rows * 48 cols (u16 elements)
#define PANEL 2408448u

__device__ __forceinline__ u16 f32_bf16(float f){
  u32 u = __builtin_bit_cast(u32, f);
  u = (u + 0x7FFFu + ((u >> 16) & 1u)) >> 16;
  return (u16)u;
}

__device__ __forceinline__ void async_cp16(const u16* g, u16* l){
  __builtin_amdgcn_global_load_lds((const __attribute__((address_space(1))) u32*)g,
                                   (__attribute__((address_space(3))) u32*)l, 16, 0, 0);
}

// ---------------------------------------------------------------- cvt x -> bf16
__global__ __launch_bounds__(256)
void cvt_f32_bf16(const float* __restrict__ in, u16* __restrict__ out){
  size_t i = ((size_t)blockIdx.x * 256 + threadIdx.x) * 8;
  f32x4 a = *(const f32x4*)(in + i);
  f32x4 b = *(const f32x4*)(in + i + 4);
  u16x8 o;
  o[0]=f32_bf16(a[0]); o[1]=f32_bf16(a[1]); o[2]=f32_bf16(a[2]); o[3]=f32_bf16(a[3]);
  o[4]=f32_bf16(b[0]); o[5]=f32_bf16(b[1]); o[6]=f32_bf16(b[2]); o[7]=f32_bf16(b[3]);
  *(u16x8*)(out + i) = o;
}

// ------------------------------------------------- transpose+cvt weights (K,N)->(N,K)
__global__ __launch_bounds__(256)
void transpose_cvt(const float* __restrict__ w, u16* __restrict__ wt, int K, int N){
  __shared__ float tile[32][33];
  int n0 = blockIdx.x * 32, k0 = blockIdx.y * 32;
  int tx = threadIdx.x, ty = threadIdx.y;   // 32 x 8
#pragma unroll
  for (int j = 0; j < 32; j += 8) tile[ty + j][tx] = w[(size_t)(k0 + ty + j) * N + n0 + tx];
  __syncthreads();
#pragma unroll
  for (int j = 0; j < 32; j += 8)
    wt[(size_t)(n0 + ty + j) * K + k0 + tx] = f32_bf16(tile[tx][ty + j]);
}

// --------------------------------------------- m97-style bf16 GEMM: C = A @ Bt^T
// 128x128 tile, BK=64, XOR-swizzled LDS (conflict-free, verified r2).
// A_GATHER: A is head-major panels [16][50176][48]; gather by k0->(head,d).
// C_HEADS:  C written bf16 scattered to panels [which*16+h][m][48].
template<int OUT_BF16, int BIAS, int A_GATHER, int C_HEADS>
__global__ __launch_bounds__(256)
void gemm_bt(const u16* __restrict__ A, const u16* __restrict__ Bt,
             void* __restrict__ Cv, const float* __restrict__ bias,
             int K, int lda, int ldc){
  __shared__ u16 sA[128 * 64];
  __shared__ u16 sB[128 * 64];
  const int tid  = threadIdx.x;
  const int lane = tid & 63;
  const int wave = tid >> 6;
  const int lrow = lane & 15, quad = lane >> 4;
  const int m0 = blockIdx.y * 128, n0 = blockIdx.x * 128;
  const int wm = (wave & 1) * 64, wn = (wave >> 1) * 64;
  const int sw = lrow & 7;
  const int col0 = ((0 * 4 + quad) ^ sw) * 8;
  const int col1 = ((1 * 4 + quad) ^ sw) * 8;

  f32x4 acc[4][4];
#pragma unroll
  for (int i = 0; i < 4; i++)
#pragma unroll
    for (int j = 0; j < 4; j++) acc[i][j] = (f32x4){0.f, 0.f, 0.f, 0.f};

  for (int kt = 0; kt < K; kt += 64){
#pragma unroll
    for (int i = 0; i < 4; i++){
      int c = i * 256 + tid;
      int m = c >> 3, kc = (c & 7) ^ (m & 7);    // inverse swizzle on global source
      const u16* src;
      if (A_GATHER){
        unsigned k0 = (unsigned)(kt + kc * 8);
        unsigned hh = k0 / 48u;
        unsigned dd = k0 - hh * 48u;
        src = A + (size_t)hh * PANEL + (size_t)(m0 + m) * 48 + dd;
      } else {
        src = A + (size_t)(m0 + m) * lda + kt + kc * 8;
      }
      async_cp16(src, &sA[c * 8]);
    }
#pragma unroll
    for (int i = 0; i < 4; i++){
      int c = i * 256 + tid;
      int n = c >> 3, kc = (c & 7) ^ (n & 7);
      async_cp16(Bt + (size_t)(n0 + n) * K + kt + kc * 8, &sB[c * 8]);
    }
    __syncthreads();
#pragma unroll
    for (int kk = 0; kk < 2; kk++){
      const int col = kk ? col1 : col0;
      bf16x8 af[4], bfv[4];
#pragma unroll
      for (int mi = 0; mi < 4; mi++)
        af[mi] = *(const bf16x8*)&sA[(wm + mi * 16 + lrow) * 64 + col];
#pragma unroll
      for (int ni = 0; ni < 4; ni++)
        bfv[ni] = *(const bf16x8*)&sB[(wn + ni * 16 + lrow) * 64 + col];
#pragma unroll
      for (int mi = 0; mi < 4; mi++)
#pragma unroll
        for (int ni = 0; ni < 4; ni++)
          acc[mi][ni] = MFMA16(af[mi], bfv[ni], acc[mi][ni]);
    }
    __syncthreads();
  }
#pragma unroll
  for (int mi = 0; mi < 4; mi++){
#pragma unroll
    for (int ni = 0; ni < 4; ni++){
      int col = n0 + wn + ni * 16 + lrow;
      if (OUT_BF16 && C_HEADS){
        unsigned which = (unsigned)col / 768u;
        unsigned rem   = (unsigned)col - which * 768u;
        unsigned hh    = rem / 48u;
        unsigned dd    = rem - hh * 48u;
        u16* cb = (u16*)Cv + (size_t)(which * 16u + hh) * PANEL + dd;
#pragma unroll
        for (int r = 0; r < 4; r++){
          int row = m0 + wm + mi * 16 + quad * 4 + r;
          cb[(size_t)row * 48] = f32_bf16(acc[mi][ni][r]);
        }
      } else {
        float bv = BIAS ? bias[col] : 0.f;
#pragma unroll
        for (int r = 0; r < 4; r++){
          int row = m0 + wm + mi * 16 + quad * 4 + r;
          float v = acc[mi][ni][r];
          if (OUT_BF16) ((u16*)Cv)[(size_t)row * ldc + col] = f32_bf16(v);
          else          ((float*)Cv)[(size_t)row * ldc + col] = v + bv;
        }
      }
    }
  }
}

// ---------------------------------------- per-(b,h): S=Q K^T (over n), norms, softmax
// qkv2 panels: q at panel h, k at panel 16+h; each [3136 x 48] contiguous per b.
__global__ __launch_bounds__(256)
void attn_stats(const u16* __restrict__ qkv2, const float* __restrict__ temperature,
                u16* __restrict__ attnb){
  const int h = blockIdx.x, b = blockIdx.y;
  const int tid = threadIdx.x, wave = tid >> 6, lane = tid & 63;
  const int lrow = lane & 15, quad = lane >> 4;
  __shared__ struct {
    union {
      struct { u16 q[48 * 136]; u16 k[48 * 136]; } t;
      float red[2 * 15 * 256];
    } u;
    float S[48 * 49];
    float invq[48], invk[48];
  } sm;

  f32x4 acc[15];
#pragma unroll
  for (int t = 0; t < 15; t++) acc[t] = (f32x4){0.f, 0.f, 0.f, 0.f};

  const u16* qbase = qkv2 + (size_t)h        * PANEL + (size_t)b * 3136 * 48;
  const u16* kbase = qkv2 + (size_t)(16 + h) * PANEL + (size_t)b * 3136 * 48;

  for (int n0 = 0; n0 < 3136; n0 += 128){
    __syncthreads();
    // 12 wave-groups: (qk 0..1) x (dg 0..5); lane = row-pair index (conflict-free b32)
#pragma unroll
    for (int i = 0; i < 3; i++){
      int wgrp = i * 4 + wave;          // 0..11, wave-uniform
      int qk = wgrp >= 6;
      int dg = qk ? wgrp - 6 : wgrp;
      int n  = n0 + lane * 2;
      const u16* src = (qk ? kbase : qbase) + (size_t)n * 48 + dg * 8;
      u16x8 va = (n     < 3136) ? *(const u16x8*)src        : (u16x8){0,0,0,0,0,0,0,0};
      u16x8 vb = (n + 1 < 3136) ? *(const u16x8*)(src + 48) : (u16x8){0,0,0,0,0,0,0,0};
      u16* dst = qk ? sm.u.t.k : sm.u.t.q;
#pragma unroll
      for (int j = 0; j < 8; j++)
        *(u32*)&dst[(dg * 8 + j) * 136 + lane * 2] = (u32)va[j] | ((u32)vb[j] << 16);
    }
    __syncthreads();
    bf16x8 qf[3], kf[3];
#pragma unroll
    for (int ti = 0; ti < 3; ti++){
      qf[ti] = *(const bf16x8*)&sm.u.t.q[(ti * 16 + lrow) * 136 + wave * 32 + quad * 8];
      kf[ti] = *(const bf16x8*)&sm.u.t.k[(ti * 16 + lrow) * 136 + wave * 32 + quad * 8];
    }
#pragma unroll
    for (int ti = 0; ti < 3; ti++)
#pragma unroll
      for (int tj = 0; tj < 3; tj++)
        acc[ti * 3 + tj] = MFMA16(qf[ti], kf[tj], acc[ti * 3 + tj]);
#pragma unroll
    for (int ti = 0; ti < 3; ti++){
      acc[9  + ti] = MFMA16(qf[ti], qf[ti], acc[9  + ti]);   // Q Q^T (diag = sumsq q)
      acc[12 + ti] = MFMA16(kf[ti], kf[ti], acc[12 + ti]);   // K K^T (diag = sumsq k)
    }
  }
  __syncthreads();
  if (wave < 2){
#pragma unroll
    for (int t = 0; t < 15; t++)
      *(f32x4*)&sm.u.red[(wave * 15 + t) * 256 + lane * 4] = acc[t];
  }
  __syncthreads();
  if (wave >= 2){
#pragma unroll
    for (int t = 0; t < 15; t++){
      f32x4* p = (f32x4*)&sm.u.red[((wave - 2) * 15 + t) * 256 + lane * 4];
      *p = *p + acc[t];
    }
  }
  __syncthreads();
  {
    const int p = tid;
    const int lr = p >> 2, rr = p & 3;
    const int row16 = ((lr >> 4) << 2) + rr, col16 = lr & 15;
#pragma unroll
    for (int t = 0; t < 9; t++){
      float v = sm.u.red[t * 256 + p] + sm.u.red[(15 + t) * 256 + p];
      sm.S[((t / 3) * 16 + row16) * 49 + (t % 3) * 16 + col16] = v;
    }
#pragma unroll
    for (int t = 9; t < 15; t++){
      float v = sm.u.red[t * 256 + p] + sm.u.red[(15 + t) * 256 + p];
      if (row16 == col16){
        if (t < 12) sm.invq[(t - 9)  * 16 + row16] = v;
        else        sm.invk[(t - 12) * 16 + row16] = v;
      }
    }
  }
  __syncthreads();
  if (tid < 96){
    float* arr = (tid < 48) ? sm.invq : sm.invk;
    int d = (tid < 48) ? tid : tid - 48;
    arr[d] = 1.0f / fmaxf(sqrtf(arr[d]), 1e-12f);
  }
  __syncthreads();
  if (tid < 48){
    const int d = tid;
    const float scale = sm.invq[d] * temperature[h];
    float lg[48];
    float mx = -1e30f;
#pragma unroll
    for (int e = 0; e < 48; e++){
      lg[e] = sm.S[d * 49 + e] * scale * sm.invk[e];
      mx = fmaxf(mx, lg[e]);
    }
    float s = 0.f;
#pragma unroll
    for (int e = 0; e < 48; e++){ float ex = __expf(lg[e] - mx); lg[e] = ex; s += ex; }
    const float inv = 1.f / s;
    u16* dst = attnb + ((size_t)(b * 16 + h) * 48 + d) * 64;
#pragma unroll
    for (int e = 0; e < 48; e++) dst[e] = f32_bf16(lg[e] * inv);
#pragma unroll
    for (int e = 48; e < 64; e++) dst[e] = 0;
  }
}

// --------------------------- out_mid[h][m][d] = sum_e attn[b,h,d,e] * v_panel[32+h][m][e]
// writes into the dead q-panels (0..15) of qkv2 — contiguous read AND write.
__global__ __launch_bounds__(256)
void attn_apply_v(const u16* __restrict__ qkv2, const u16* __restrict__ attnb,
                  u16* __restrict__ outm){
  const int h = blockIdx.y, b = blockIdx.z;
  const int nb = blockIdx.x * 256;
  const int tid = threadIdx.x, wave = tid >> 6, lane = tid & 63;
  const int lrow = lane & 15, quad = lane >> 4;
  __shared__ u16 sA[48 * 72];
#pragma unroll
  for (int i = 0; i < 2; i++){
    int idx = i * 256 + tid;
    if (idx < 384){
      int d = idx >> 3, eg = idx & 7;
      *(u16x8*)&sA[d * 72 + eg * 8] =
        *(const u16x8*)&attnb[((size_t)(b * 16 + h) * 48 + d) * 64 + eg * 8];
    }
  }
  __syncthreads();
  bf16x8 bfr[3][2];
#pragma unroll
  for (int tj = 0; tj < 3; tj++){
    bfr[tj][0] = *(const bf16x8*)&sA[(tj * 16 + lrow) * 72 + quad * 8];
    bfr[tj][1] = *(const bf16x8*)&sA[(tj * 16 + lrow) * 72 + 32 + quad * 8];
  }
  f32x4 acc[4][3];
#pragma unroll
  for (int i = 0; i < 4; i++)
#pragma unroll
    for (int j = 0; j < 3; j++) acc[i][j] = (f32x4){0.f, 0.f, 0.f, 0.f};

  const u16* vpanel = qkv2 + (size_t)(32 + h) * PANEL + (size_t)b * 3136 * 48;
  const int eo1 = 32 + ((quad < 2) ? quad * 8 : 0);   // clamp e>=48 lanes (B there is 0)
#pragma unroll
  for (int mi = 0; mi < 4; mi++){
    int n = nb + wave * 64 + mi * 16 + lrow;
    int nc = n < 3136 ? n : 3135;
    const u16* vp = vpanel + (size_t)nc * 48;
    bf16x8 a0 = *(const bf16x8*)(vp + quad * 8);
    bf16x8 a1 = *(const bf16x8*)(vp + eo1);
#pragma unroll
    for (int tj = 0; tj < 3; tj++){
      acc[mi][tj] = MFMA16(a0, bfr[tj][0], acc[mi][tj]);
      acc[mi][tj] = MFMA16(a1, bfr[tj][1], acc[mi][tj]);
    }
  }
  u16* opanel = outm + (size_t)h * PANEL + (size_t)b * 3136 * 48;
#pragma unroll
  for (int mi = 0; mi < 4; mi++)
#pragma unroll
    for (int tj = 0; tj < 3; tj++){
      int d = tj * 16 + lrow;
#pragma unroll
      for (int r = 0; r < 4; r++){
        int n = nb + wave * 64 + mi * 16 + quad * 4 + r;
        if (n < 3136) opanel[(size_t)n * 48 + d] = f32_bf16(acc[mi][tj][r]);
      }
    }
}

extern "C" void kernel_launch(void* const* d_in, const int* in_sizes, int n_in,
                              void* d_out, int out_size, void* d_ws, size_t ws_size,
                              hipStream_t stream){
  const float* x      = (const float*)d_in[0];   // [16,3136,768]
  const float* qkv_w  = (const float*)d_in[1];   // [768,2304]
  const float* temp   = (const float*)d_in[2];   // [16]
  const float* proj_w = (const float*)d_in[3];   // [768,768]
  const float* proj_b = (const float*)d_in[4];   // [768]
  float* out = (float*)d_out;
  char* ws = (char*)d_ws;

  // workspace layout (bytes)
  const size_t OFF_XB   = 0;            // 50176*768*2   = 77,070,336
  const size_t OFF_WQ   = 77070336;     // 2304*768*2    =  3,538,944
  const size_t OFF_WP   = 80609280;     // 768*768*2     =  1,179,648
  const size_t OFF_QKV  = 81788928;     // 48 panels * 2408448 u16 * 2 = 231,211,008
  const size_t OFF_ATTN = 312999936;    // 16*16*48*64*2 =  1,572,864  (end ~314.6 MB)

  u16* xb    = (u16*)(ws + OFF_XB);
  u16* wqt   = (u16*)(ws + OFF_WQ);
  u16* wpt   = (u16*)(ws + OFF_WP);
  u16* qkv2  = (u16*)(ws + OFF_QKV);   // panels: q 0..15, k 16..31, v 32..47
  u16* attnb = (u16*)(ws + OFF_ATTN);

  // 1) casts / transposes
  cvt_f32_bf16<<<dim3(18816), dim3(256), 0, stream>>>(x, xb);
  transpose_cvt<<<dim3(2304 / 32, 768 / 32), dim3(32, 8), 0, stream>>>(qkv_w, wqt, 768, 2304);
  transpose_cvt<<<dim3(768 / 32, 768 / 32), dim3(32, 8), 0, stream>>>(proj_w, wpt, 768, 768);
  // 2) qkv = x @ qkv_w, scattered to head-major panels
  gemm_bt<1, 0, 0, 1><<<dim3(18, 392), dim3(256), 0, stream>>>(xb, wqt, qkv2, nullptr, 768, 768, 0);
  // 3) per-(b,h) Gram + norms + softmax -> attn [B,H,48,64] (cols 48..63 zero)
  attn_stats<<<dim3(16, 16), dim3(256), 0, stream>>>(qkv2, temp, attnb);
  // 4) attn @ v -> dead q-panels (0..15) as out_mid [h][m][48]
  attn_apply_v<<<dim3(13, 16, 16), dim3(256), 0, stream>>>(qkv2, attnb, qkv2);
  // 5) out = out_mid @ proj_w + proj_b (fp32 out), A gathered from head panels
  gemm_bt<0, 1, 1, 0><<<dim3(6, 392), dim3(256), 0, stream>>>(qkv2, wpt, out, proj_b, 768, 0, 768);
}